// Round 5
// baseline (295.050 us; speedup 1.0000x reference)
//
#include <hip/hip_runtime.h>
#include <hip/hip_bf16.h>
#include <stdint.h>

#define M_TOK 32
#define IN_F 4096
#define OUT_F 11008
#define NSPLIT 8
#define KRANGE (IN_F / NSPLIT)   // 512 k per block
#define NSTEP  (KRANGE / 32)     // 16 MFMA k-steps per block
#define NKK    (IN_F / 32)       // 128 global k-steps

typedef __attribute__((ext_vector_type(8))) short bf16x8;
typedef __attribute__((ext_vector_type(4))) float f32x4;

__device__ inline uint32_t pack_bf16(float a, float b) {
    __hip_bfloat16 ha = __float2bfloat16(a);
    __hip_bfloat16 hb = __float2bfloat16(b);
    uint16_t ua = *(uint16_t*)&ha;
    uint16_t ub = *(uint16_t*)&hb;
    return (uint32_t)ua | ((uint32_t)ub << 16);
}

// out[m][o] = bias[o]   (grid: 43 x 32, block 256 — exact cover of 11008 x 32)
__global__ void init_out_kernel(const float* __restrict__ bias, float* __restrict__ out) {
    int o = blockIdx.x * 256 + threadIdx.x;
    int m = blockIdx.y;
    out[(size_t)m * OUT_F + o] = bias[o];
}

// Pre-pack x into MFMA A-fragments (bf16), fragment-ordered:
// af[kk*128 + j*64 + lane] ; lane (lm,lq) of frag j holds
// x[m = lm + 16*j][kk*32 + lq*8 .. +8] as bf16x8.
__global__ void prepack_a_kernel(const float* __restrict__ x, uint4* __restrict__ ws4) {
    int u  = blockIdx.x * 256 + threadIdx.x;   // 0..8191
    int kk = u >> 6;
    int l  = u & 63;
    int lm = l & 15;
    int lq = l >> 4;
    int kb = kk * 32 + lq * 8;
    #pragma unroll
    for (int j = 0; j < 2; ++j) {
        const float* xp = x + (size_t)(lm + 16 * j) * IN_F + kb;
        union { uint4 q; uint32_t u[4]; } f;
        f.u[0] = pack_bf16(xp[0], xp[1]);
        f.u[1] = pack_bf16(xp[2], xp[3]);
        f.u[2] = pack_bf16(xp[4], xp[5]);
        f.u[3] = pack_bf16(xp[6], xp[7]);
        ws4[(size_t)kk * 128 + j * 64 + l] = f.q;
    }
}

// Repack int32 weights (values 0..15) into nibble-packed dwords, laid out
// fragment-ordered for qgemm:
//   pw[ ((nb*8 + ks)*16 + s)*256 + rloc*4 + lq ] = nibbles of
//   W[nb*64 + rloc][ks*512 + s*32 + lq*8 .. +8]   (nibble i = k-offset i)
// INPUT is read as a perfectly linear stream (fill-shaped: each wave reads
// 2 KB contiguous; 4-KB granules per row within a block tile) — this is the
// whole point: the 180 MB read happens at fill BW, not at qgemm's scattered-
// granule BW. Output lines are assembled in LDS and written as full 64-B
// segments (block tile = 4 aligned rows x 1024 k -> 32 slices x 16 dwords).
__global__ void repack_w_kernel(const int* __restrict__ wq, uint32_t* __restrict__ pw) {
    __shared__ uint32_t lds32[32 * 16];   // 2 KB staging
    const int b     = blockIdx.x;
    const int rg    = b >> 2;             // row-group of 4 rows (4-aligned)
    const int chunk = b & 3;              // which 1024-k chunk
    const int t     = threadIdx.x;
    const int row   = rg * 4 + (t >> 6);
    const int K0    = chunk * 1024;
    const int koff  = (t & 63) * 8;
    const int s_l   = (t & 63) >> 2;      // s within the 512-k half
    const int didx  = (t >> 6) * 4 + (t & 3);   // local row * 4 + lq

    #pragma unroll
    for (int it = 0; it < 2; ++it) {
        const int* ip = wq + (size_t)row * IN_F + K0 + it * 512 + koff;
        int4 qa = *(const int4*)ip;
        int4 qb = *(const int4*)(ip + 4);
        uint32_t w = (uint32_t)(qa.x & 15)
                   | ((uint32_t)(qa.y & 15) << 4)
                   | ((uint32_t)(qa.z & 15) << 8)
                   | ((uint32_t)(qa.w & 15) << 12)
                   | ((uint32_t)(qb.x & 15) << 16)
                   | ((uint32_t)(qb.y & 15) << 20)
                   | ((uint32_t)(qb.z & 15) << 24)
                   | ((uint32_t)(qb.w & 15) << 28);
        lds32[(it * 16 + s_l) * 16 + didx] = w;
    }
    __syncthreads();

    // writeback: thread t covers slice = t>>3 (0..31), dword-pair = t&7
    const int slice = t >> 3;
    const int pair  = t & 7;
    const int it_w  = slice >> 4;
    const int s_w   = slice & 15;
    const int ks_w  = chunk * 2 + it_w;
    const int nb    = rg >> 4;            // (rg*4)>>6
    const int rloc0 = (rg & 15) * 4;      // (rg*4)&63
    size_t base = ((size_t)(nb * 8 + ks_w) * 16 + s_w) * 256 + rloc0 * 4;
    *(uint2*)(pw + base + pair * 2) = *(const uint2*)(&lds32[slice * 16 + pair * 2]);
}

// qgemm v2: packed weights (22.5 MB, L2/L3-resident) read direct — no LDS,
// no barriers, no manual waitcnt. Per lane per step: 1 packed dword
// (wave-contiguous 256 B), 2 A-frag uint4 (wave-contiguous 1 KB, L2), 1
// float2 sz, nibble-unpack, 2 MFMA. Latency hidden by TLP + unroll ILP.
__launch_bounds__(256)
__global__ void qgemm_kernel(const uint4* __restrict__ af,
                             const uint32_t* __restrict__ pw,
                             const float* __restrict__ sz,
                             float* __restrict__ out) {
    const int bid = blockIdx.x;
    const int ks  = bid & (NSPLIT - 1);
    const int nb  = bid >> 3;
    const int t   = threadIdx.x;
    const int wv  = t >> 6;
    const int l   = t & 63;
    const int lm  = l & 15;
    const int lq  = l >> 4;
    const int rloc = wv * 16 + lm;
    const int row  = nb * 64 + rloc;      // out-feature row this lane computes

    const uint32_t* wp = pw + ((size_t)(nb * 8 + ks) * 16) * 256 + rloc * 4 + lq;
    const uint4*    ap = af + (size_t)ks * (NSTEP * 128) + l;
    const float*   szp = sz + ((size_t)(ks * 16) * OUT_F + row) * 2;

    f32x4 acc0 = {0.f, 0.f, 0.f, 0.f};
    f32x4 acc1 = {0.f, 0.f, 0.f, 0.f};

    #pragma unroll 4
    for (int s = 0; s < NSTEP; ++s) {
        uint32_t w  = wp[s * 256];
        float2   sv = *(const float2*)(szp);
        union { uint4 q; bf16x8 v; } a0, a1;
        a0.q = ap[s * 128];
        a1.q = ap[s * 128 + 64];
        szp += (size_t)OUT_F * 2;

        const uint32_t we = w & 0x0F0F0F0Fu;          // nibbles 0,2,4,6 as bytes
        const uint32_t no = (w >> 4) & 0x0F0F0F0Fu;   // nibbles 1,3,5,7 as bytes
        const float sc = sv.x;
        const float zp = sv.y - 8.0f * sv.x;          // fold -8 midpoint into zero

        union { bf16x8 v; uint32_t u[4]; } bf;
        bf.u[0] = pack_bf16((float)(we & 0xffu) * sc + zp,
                            (float)(no & 0xffu) * sc + zp);
        bf.u[1] = pack_bf16((float)((we >> 8) & 0xffu) * sc + zp,
                            (float)((no >> 8) & 0xffu) * sc + zp);
        bf.u[2] = pack_bf16((float)((we >> 16) & 0xffu) * sc + zp,
                            (float)((no >> 16) & 0xffu) * sc + zp);
        bf.u[3] = pack_bf16((float)(we >> 24) * sc + zp,
                            (float)(no >> 24) * sc + zp);

        acc0 = __builtin_amdgcn_mfma_f32_16x16x32_bf16(a0.v, bf.v, acc0, 0, 0, 0);
        acc1 = __builtin_amdgcn_mfma_f32_16x16x32_bf16(a1.v, bf.v, acc1, 0, 0, 0);
    }

    // epilogue: D col(lane&15)=n, row((lane>>4)*4+i)=m  (verified R0)
    const int ocol = row;
    #pragma unroll
    for (int i = 0; i < 4; ++i) {
        int m0 = lq * 4 + i;
        atomicAdd(&out[(size_t)m0 * OUT_F + ocol], acc0[i]);
        atomicAdd(&out[(size_t)(16 + m0) * OUT_F + ocol], acc1[i]);
    }
}

extern "C" void kernel_launch(void* const* d_in, const int* in_sizes, int n_in,
                              void* d_out, int out_size, void* d_ws, size_t ws_size,
                              hipStream_t stream) {
    const float* x    = (const float*)d_in[0];   // [32, 4096] fp32
    const int*   wq   = (const int*)d_in[1];     // [11008, 4096] int32 (0..15)
    const float* sz   = (const float*)d_in[2];   // [128, 11008, 2] fp32
    const float* bias = (const float*)d_in[3];   // [11008] fp32
    float* out = (float*)d_out;                  // [32, 11008] fp32

    uint4*    af = (uint4*)d_ws;                          // 256 KB A-fragments
    uint32_t* pw = (uint32_t*)((char*)d_ws + (1 << 20));  // 22.5 MB packed weights

    // 1) linear-stream repack of the 180 MB weight tensor (fill-shaped read)
    repack_w_kernel<<<dim3((OUT_F / 4) * 4), 256, 0, stream>>>(wq, pw);

    // 2) tiny prep kernels
    prepack_a_kernel<<<dim3(NKK * 64 / 256), 256, 0, stream>>>(x, af);
    dim3 gi(OUT_F / 256, M_TOK);                 // 43 x 32
    init_out_kernel<<<gi, 256, 0, stream>>>(bias, out);

    // 3) GEMM on packed weights
    dim3 gg((OUT_F / 64) * NSPLIT);              // 172 * 8 = 1376 blocks
    qgemm_kernel<<<gg, 256, 0, stream>>>(af, pw, sz, out);
}

// Round 6
// 275.242 us; speedup vs baseline: 1.0720x; 1.0720x over previous
//
#include <hip/hip_runtime.h>
#include <hip/hip_bf16.h>
#include <stdint.h>

#define M_TOK 32
#define IN_F 4096
#define OUT_F 11008
#define NSPLIT 2
#define KRANGE (IN_F / NSPLIT)   // 2048 k per block
#define NST    (KRANGE / 32)     // 64 MFMA k-steps per block
#define NKK    (IN_F / 32)       // 128 global k-steps

typedef __attribute__((ext_vector_type(8))) short bf16x8;
typedef __attribute__((ext_vector_type(4))) float f32x4;

__device__ inline uint32_t pack_bf16(float a, float b) {
    __hip_bfloat16 ha = __float2bfloat16(a);
    __hip_bfloat16 hb = __float2bfloat16(b);
    uint16_t ua = *(uint16_t*)&ha;
    uint16_t ub = *(uint16_t*)&hb;
    return (uint32_t)ua | ((uint32_t)ub << 16);
}

// out[m][o] = bias[o]   (grid: 43 x 32, block 256 — exact cover of 11008 x 32)
__global__ void init_out_kernel(const float* __restrict__ bias, float* __restrict__ out) {
    int o = blockIdx.x * 256 + threadIdx.x;
    int m = blockIdx.y;
    out[(size_t)m * OUT_F + o] = bias[o];
}

// Pre-pack x into MFMA A-fragments (bf16), fragment-ordered:
// af[kk*128 + j*64 + lane] ; lane (lm,lq) of frag j holds
// x[m = lm + 16*j][kk*32 + lq*8 .. +8] as bf16x8.
__global__ void prepack_a_kernel(const float* __restrict__ x, uint4* __restrict__ ws4) {
    int u  = blockIdx.x * 256 + threadIdx.x;   // 0..8191
    int kk = u >> 6;
    int l  = u & 63;
    int lm = l & 15;
    int lq = l >> 4;
    int kb = kk * 32 + lq * 8;
    #pragma unroll
    for (int j = 0; j < 2; ++j) {
        const float* xp = x + (size_t)(lm + 16 * j) * IN_F + kb;
        union { uint4 q; uint32_t u[4]; } f;
        f.u[0] = pack_bf16(xp[0], xp[1]);
        f.u[1] = pack_bf16(xp[2], xp[3]);
        f.u[2] = pack_bf16(xp[4], xp[5]);
        f.u[3] = pack_bf16(xp[6], xp[7]);
        ws4[(size_t)kk * 128 + j * 64 + l] = f.q;
    }
}

// Barrier-free, per-wave-independent deep-pipelined dequant-GEMM.
// Each wave owns 16 out-rows and stages ONLY its own rows into its private
// quarter of the LDS ring -> no cross-wave dependency -> NO s_barrier at all.
// Per step (one vmem "group", all in one wave's in-order vmcnt queue):
//   2x global_load_lds (own 16 weight rows, source-side XOR swizzle)
//   2x global_load_dwordx4 (A-frags -> named VGPR ring, 3 steps ahead)
//   1x global_load_dwordx2 (scale/zero -> VGPR ring)
// WAITV(10) retires group s exactly (groups s+1,s+2 = 10 ops outstanding);
// sched_barrier(0) at each WAITV fences groups so the ledger stays exact and
// step-s ds_reads are captured before the slot-reusing gll of step s+4 issues.
__launch_bounds__(256)
__global__ void qgemm_kernel(const uint4* __restrict__ af,
                             const int* __restrict__ wq,
                             const float* __restrict__ sz,
                             float* __restrict__ out) {
    __shared__ int lds_w[4][2048];   // 4 x 8 KB ring; wave wv owns dwords [wv*512,+512)

    const int bid = blockIdx.x;
    const int ks  = bid & (NSPLIT - 1);
    const int nb  = bid >> 1;
    const int t   = threadIdx.x;
    const int wv  = t >> 6;
    const int l   = t & 63;
    const int lm  = l & 15;
    const int lq  = l >> 4;

    const int row0 = nb * 64;
    const int row  = row0 + wv * 16 + lm;    // out-feature row this lane computes
    const int k0   = ks * KRANGE;

    // staging (per wave, self-contained): gll A covers local rows 0-7, gll B
    // rows 8-15. Lane l: row-local rr = l>>3, chunk slot cc = l&7; fetch
    // global chunk (cc ^ rr) so LDS slot c of row r holds chunk c^(r&7).
    const int rr   = l >> 3;
    const int cc   = l & 7;
    const int* gwa = wq + (size_t)(row0 + wv * 16 + rr) * IN_F + k0 + ((cc ^ rr) * 4);
    const int* gwb = gwa + (size_t)8 * IN_F;

    // reader (swizzle inverted): row-local lm, global chunks 2lq, 2lq+1.
    const int c0 = wv * 512 + lm * 32 + (((2 * lq)     ^ (lm & 7)) * 4);
    const int c1 = wv * 512 + lm * 32 + (((2 * lq + 1) ^ (lm & 7)) * 4);

    const uint4* ap  = af + (size_t)(ks * NST) * 128 + l;
    const float* szp = sz + ((size_t)(ks * NST) * OUT_F + row) * 2;

#define GLL(src, dst) \
    __builtin_amdgcn_global_load_lds( \
        (const __attribute__((address_space(1))) int*)(src), \
        (__attribute__((address_space(3))) int*)(dst), 16, 0, 0)

#define WAITV(N) do {                                         \
    asm volatile("s_waitcnt vmcnt(" #N ")" ::: "memory");     \
    __builtin_amdgcn_sched_barrier(0);                        \
} while (0)

    uint4  A0_0, A0_1, A0_2, A0_3;     // A-frag ring (rows 0-15 of M)
    uint4  A1_0, A1_1, A1_2, A1_3;     // A-frag ring (rows 16-31 of M)
    float2 S_0,  S_1,  S_2,  S_3;      // scale/zero ring

#define PREFETCH(slot, stepexpr) do {                                   \
    const int _s = (stepexpr);                                          \
    GLL(gwa + (size_t)_s * 32, &lds_w[slot][wv * 512]);                 \
    GLL(gwb + (size_t)_s * 32, &lds_w[slot][wv * 512 + 256]);           \
    A0_##slot = ap[(size_t)_s * 128];                                   \
    A1_##slot = ap[(size_t)_s * 128 + 64];                              \
    S_##slot  = *(const float2*)(szp + (size_t)_s * OUT_F * 2);         \
} while (0)

    f32x4 acc0 = {0.f, 0.f, 0.f, 0.f};
    f32x4 acc1 = {0.f, 0.f, 0.f, 0.f};

#define COMPUTE(slot) do {                                                      \
    int4 q0 = *(const int4*)(&lds_w[slot][c0]);                                 \
    int4 q1 = *(const int4*)(&lds_w[slot][c1]);                                 \
    const float sc = S_##slot.x;                                                \
    const float zp = S_##slot.y - 8.0f * sc;                                    \
    union { uint4 q; bf16x8 v; } ua, ub;                                        \
    ua.q = A0_##slot;                                                           \
    ub.q = A1_##slot;                                                           \
    union { bf16x8 v; uint32_t u[4]; } bf;                                      \
    bf.u[0] = pack_bf16((float)q0.x * sc + zp, (float)q0.y * sc + zp);          \
    bf.u[1] = pack_bf16((float)q0.z * sc + zp, (float)q0.w * sc + zp);          \
    bf.u[2] = pack_bf16((float)q1.x * sc + zp, (float)q1.y * sc + zp);          \
    bf.u[3] = pack_bf16((float)q1.z * sc + zp, (float)q1.w * sc + zp);          \
    acc0 = __builtin_amdgcn_mfma_f32_16x16x32_bf16(ua.v, bf.v, acc0, 0, 0, 0);  \
    acc1 = __builtin_amdgcn_mfma_f32_16x16x32_bf16(ub.v, bf.v, acc1, 0, 0, 0);  \
} while (0)

    // prologue: groups 0,1,2 in flight (15 vmem ops)
    PREFETCH(0, 0);
    PREFETCH(1, 1);
    PREFETCH(2, 2);
    __builtin_amdgcn_sched_barrier(0);

    // main: steps 0..59 (slot = step & 3), prefetch steps 3..62
    #pragma unroll 1
    for (int u = 0; u < 15; ++u) {
        const int sb = u * 4;
        WAITV(10); PREFETCH(3, sb + 3); COMPUTE(0);
        WAITV(10); PREFETCH(0, sb + 4); COMPUTE(1);
        WAITV(10); PREFETCH(1, sb + 5); COMPUTE(2);
        WAITV(10); PREFETCH(2, sb + 6); COMPUTE(3);
    }
    // steps 60..63 (prefetched through 62; fetch 63 here)
    WAITV(10); PREFETCH(3, 63); COMPUTE(0);
    WAITV(10); COMPUTE(1);
    WAITV(5);  COMPUTE(2);
    WAITV(0);  COMPUTE(3);

#undef COMPUTE
#undef PREFETCH
#undef GLL
#undef WAITV

    // epilogue: D col(lane&15)=n, row((lane>>4)*4+i)=m  (verified R0)
    const int ocol = row;
    #pragma unroll
    for (int i = 0; i < 4; ++i) {
        int m0 = lq * 4 + i;
        atomicAdd(&out[(size_t)m0 * OUT_F + ocol], acc0[i]);
        atomicAdd(&out[(size_t)(16 + m0) * OUT_F + ocol], acc1[i]);
    }
}

extern "C" void kernel_launch(void* const* d_in, const int* in_sizes, int n_in,
                              void* d_out, int out_size, void* d_ws, size_t ws_size,
                              hipStream_t stream) {
    const float* x    = (const float*)d_in[0];   // [32, 4096] fp32
    const int*   wq   = (const int*)d_in[1];     // [11008, 4096] int32 (0..15)
    const float* sz   = (const float*)d_in[2];   // [128, 11008, 2] fp32
    const float* bias = (const float*)d_in[3];   // [11008] fp32
    float* out = (float*)d_out;                  // [32, 11008] fp32
    uint4* af  = (uint4*)d_ws;                   // [128][2][64] bf16x8 A-frags (256 KB)

    prepack_a_kernel<<<dim3(NKK * 64 / 256), 256, 0, stream>>>(x, af);

    dim3 gi(OUT_F / 256, M_TOK);                 // 43 x 32
    init_out_kernel<<<gi, 256, 0, stream>>>(bias, out);

    dim3 gg((OUT_F / 64) * NSPLIT);              // 172 * 2 = 344 blocks
    qgemm_kernel<<<gg, 256, 0, stream>>>((const uint4*)af, wq, sz, out);
}

// Round 7
// 269.515 us; speedup vs baseline: 1.0947x; 1.0212x over previous
//
#include <hip/hip_runtime.h>
#include <hip/hip_bf16.h>
#include <stdint.h>

#define M_TOK 32
#define IN_F 4096
#define OUT_F 11008
#define NSPLIT 8
#define KRANGE (IN_F / NSPLIT)   // 512 k per block
#define NSTEP  (KRANGE / 32)     // 16 MFMA k-steps per block
#define NKK    (IN_F / 32)       // 128 global k-steps
#define NBUF   4                 // weight LDS tile ring (3 tiles in flight)

typedef __attribute__((ext_vector_type(8))) short bf16x8;
typedef __attribute__((ext_vector_type(4))) float f32x4;

__device__ inline uint32_t pack_bf16(float a, float b) {
    __hip_bfloat16 ha = __float2bfloat16(a);
    __hip_bfloat16 hb = __float2bfloat16(b);
    uint16_t ua = *(uint16_t*)&ha;
    uint16_t ub = *(uint16_t*)&hb;
    return (uint32_t)ua | ((uint32_t)ub << 16);
}

// Pre-pack x into MFMA A-fragments (bf16), fragment-ordered:
// af[kk*128 + j*64 + lane] ; lane (lm,lq) of frag j holds
// x[m = lm + 16*j][kk*32 + lq*8 .. +8] as bf16x8.
__global__ void prepack_a_kernel(const float* __restrict__ x, uint4* __restrict__ ws4) {
    int u  = blockIdx.x * 256 + threadIdx.x;   // 0..8191
    int kk = u >> 6;
    int l  = u & 63;
    int lm = l & 15;
    int lq = l >> 4;
    int kb = kk * 32 + lq * 8;
    #pragma unroll
    for (int j = 0; j < 2; ++j) {
        const float* xp = x + (size_t)(lm + 16 * j) * IN_F + kb;
        union { uint4 q; uint32_t u[4]; } f;
        f.u[0] = pack_bf16(xp[0], xp[1]);
        f.u[1] = pack_bf16(xp[2], xp[3]);
        f.u[2] = pack_bf16(xp[4], xp[5]);
        f.u[3] = pack_bf16(xp[6], xp[7]);
        ws4[(size_t)kk * 128 + j * 64 + l] = f.q;
    }
}

// out[m][o] = bias[o] + sum_ks partials[ks][m][o]   (grid 43 x 32, block 256)
__global__ void reduce_kernel(const float* __restrict__ part,
                              const float* __restrict__ bias,
                              float* __restrict__ out) {
    int o = blockIdx.x * 256 + threadIdx.x;
    int m = blockIdx.y;
    float s = bias[o];
    #pragma unroll
    for (int k = 0; k < NSPLIT; ++k)
        s += part[((size_t)k * M_TOK + m) * OUT_F + o];
    out[(size_t)m * OUT_F + o] = s;
}

// Deep-pipelined dequant-GEMM (R4 structure, verified 265.8). The MAIN LOOP'S
// ONLY VMEM ops are the staged weight loads, so the counted vmcnt(4) is exact.
//   prologue: stage A-frags (32 KB) + sz slice (8 KB) + weight tiles 0-2
//   per step: vmcnt(4) -> s_barrier -> STAGE(s+3) -> ds_reads+dequant+2 MFMA
// LDS: 32 KB weights (4-ring) + 32 KB A + 8 KB sz = 72 KB -> 2 blocks/CU.
// Epilogue (new in R7): plain stores to disjoint partials[ks] — NO atomics
// (old: 2.8M device-scope atomicAdds with 8-way per-address serialization).
__launch_bounds__(256)
__global__ void qgemm_kernel(const uint4* __restrict__ af,
                             const int* __restrict__ wq,
                             const float* __restrict__ sz,
                             float* __restrict__ part) {
    __shared__ int    lds_w[NBUF][64 * 32];   // 4 x 8 KB weight tiles
    __shared__ uint4  lds_a[NSTEP * 128];     // 32 KB A-fragments (this ks slice)
    __shared__ float2 lds_s[NSTEP * 64];      // 8 KB scale/zero (step-major)

    const int bid = blockIdx.x;
    const int ks  = bid & (NSPLIT - 1);
    const int nb  = bid >> 3;
    const int t   = threadIdx.x;
    const int wv  = t >> 6;
    const int l   = t & 63;
    const int lm  = l & 15;
    const int lq  = l >> 4;

    const int row0 = nb * 64;
    const int row  = row0 + wv * 16 + lm;    // out-feature row this lane computes
    const int k0   = ks * KRANGE;

    // weight staging: thread t covers tile row rs = t>>3 (+32 for issue 1),
    // chunk slot cs = t&7; fetch global chunk (cs ^ (rs&7)) so LDS slot c of
    // row r holds global chunk c^(r&7) (involution; kills 16-way read conflict).
    const int rs    = t >> 3;                // 0..31
    const int cs    = t & 7;
    const int* gw0  = wq + (size_t)(row0 + rs) * IN_F + k0 + ((cs ^ (rs & 7)) * 4);
    const int* gw1  = gw0 + (size_t)32 * IN_F;   // rows 32..63

#define GLL(src, dst) \
    __builtin_amdgcn_global_load_lds( \
        (const __attribute__((address_space(1))) int*)(src), \
        (__attribute__((address_space(3))) int*)(dst), 16, 0, 0)

#define STAGE(buf, tile) do {                                 \
    GLL(gw0 + (tile) * 32, &lds_w[(buf)][wv * 256]);          \
    GLL(gw1 + (tile) * 32, &lds_w[(buf)][1024 + wv * 256]);   \
} while (0)

#define WAITV(N) do {                                         \
    asm volatile("s_waitcnt vmcnt(" #N ")" ::: "memory");     \
    __builtin_amdgcn_sched_barrier(0);                        \
} while (0)

#define BAR() do {                                            \
    __builtin_amdgcn_s_barrier();                             \
    __builtin_amdgcn_sched_barrier(0);                        \
} while (0)

    // weight reader addresses (swizzle inverted): lane wants global chunks
    // 2*lq and 2*lq+1 of local row rloc.
    const int rloc = wv * 16 + lm;
    const int c0   = rloc * 32 + (((2 * lq)     ^ (rloc & 7)) * 4);
    const int c1   = rloc * 32 + (((2 * lq + 1) ^ (rloc & 7)) * 4);

    // ---- prologue staging (order matters for the vmcnt ledger) ----
    // A-frags: ks slice = af[ks*2048 .. +2048) uint4, contiguous 32 KB.
    {
        const uint4* asrc = af + (size_t)ks * (NSTEP * 128) + t;
        #pragma unroll
        for (int i = 0; i < 8; ++i)
            GLL(asrc + i * 256, &lds_a[i * 256 + wv * 64]);
    }
    // sz: step st, rows row0..row0+63 => 512 B contiguous per step.
    // thread t: st = t>>5 (+8 for issue 1), 16-B chunk c = t&31.
    {
        const float* szsrc = sz + ((size_t)(k0 >> 5) * OUT_F + row0) * 2
                                + (size_t)(t >> 5) * OUT_F * 2 + (t & 31) * 4;
        GLL(szsrc,                         &lds_s[wv * 128]);
        GLL(szsrc + (size_t)8 * OUT_F * 2, &lds_s[512 + wv * 128]);
    }
    STAGE(0, 0);
    STAGE(1, 1);
    STAGE(2, 2);
    __builtin_amdgcn_sched_barrier(0);
    // outstanding: A(8) + sz(2) + w(6) = 16. First WAITV(4) retires A, sz, tile0.

    f32x4 acc0 = {0.f, 0.f, 0.f, 0.f};
    f32x4 acc1 = {0.f, 0.f, 0.f, 0.f};

#define STEP_BODY(cb, st) do {                                                  \
    int4   q0 = *(const int4*)(&lds_w[(cb)][c0]);                               \
    int4   q1 = *(const int4*)(&lds_w[(cb)][c1]);                               \
    union { uint4 q; bf16x8 v; } a0, a1;                                        \
    a0.q = lds_a[(st) * 128 + l];                                               \
    a1.q = lds_a[(st) * 128 + 64 + l];                                          \
    float2 sv = lds_s[(st) * 64 + rloc];                                        \
    const float sc = sv.x;                                                      \
    const float zp = sv.y - 8.0f * sv.x;                                        \
    union { bf16x8 v; uint32_t u[4]; } bf;                                      \
    bf.u[0] = pack_bf16((float)q0.x * sc + zp, (float)q0.y * sc + zp);          \
    bf.u[1] = pack_bf16((float)q0.z * sc + zp, (float)q0.w * sc + zp);          \
    bf.u[2] = pack_bf16((float)q1.x * sc + zp, (float)q1.y * sc + zp);          \
    bf.u[3] = pack_bf16((float)q1.z * sc + zp, (float)q1.w * sc + zp);          \
    acc0 = __builtin_amdgcn_mfma_f32_16x16x32_bf16(a0.v, bf.v, acc0, 0, 0, 0);  \
    acc1 = __builtin_amdgcn_mfma_f32_16x16x32_bf16(a1.v, bf.v, acc1, 0, 0, 0);  \
} while (0)

    // main: steps 0..11, stage tiles 3..14; tiles s+1,s+2,(s+3) stay in flight
    #pragma unroll 4
    for (int s = 0; s < 12; ++s) {
        WAITV(4);                        // tile s staged; 4 loads outstanding
        BAR();
        STAGE((s + 3) & 3, s + 3);       // overwrites tile s-1's buffer (safe)
        STEP_BODY(s & 3, s);
    }
    // step 12: stage the last tile (15)
    WAITV(4); BAR(); STAGE(3, 15); STEP_BODY(0, 12);
    // steps 13..15: drain
    WAITV(4); BAR(); STEP_BODY(1, 13);
    WAITV(2); BAR(); STEP_BODY(2, 14);
    WAITV(0); BAR(); STEP_BODY(3, 15);

#undef STEP_BODY
#undef STAGE
#undef GLL
#undef WAITV
#undef BAR

    // epilogue: plain stores into this block's disjoint partial slice.
    // D col(lane&15)=n, row((lane>>4)*4+i)=m  (verified R0)
    float* pp = part + (size_t)ks * M_TOK * OUT_F;
    const int ocol = row;
    #pragma unroll
    for (int i = 0; i < 4; ++i) {
        int m0 = lq * 4 + i;
        pp[(size_t)m0 * OUT_F + ocol]        = acc0[i];
        pp[(size_t)(16 + m0) * OUT_F + ocol] = acc1[i];
    }
}

extern "C" void kernel_launch(void* const* d_in, const int* in_sizes, int n_in,
                              void* d_out, int out_size, void* d_ws, size_t ws_size,
                              hipStream_t stream) {
    const float* x    = (const float*)d_in[0];   // [32, 4096] fp32
    const int*   wq   = (const int*)d_in[1];     // [11008, 4096] int32 (0..15)
    const float* sz   = (const float*)d_in[2];   // [128, 11008, 2] fp32
    const float* bias = (const float*)d_in[3];   // [11008] fp32
    float* out = (float*)d_out;                  // [32, 11008] fp32

    uint4* af   = (uint4*)d_ws;                        // 256 KB A-fragments
    float* part = (float*)((char*)d_ws + (1 << 20));   // 11.3 MB partials [8][32][11008]

    prepack_a_kernel<<<dim3(NKK * 64 / 256), 256, 0, stream>>>(x, af);

    dim3 gg((OUT_F / 64) * NSPLIT);              // 172 * 8 = 1376 blocks
    qgemm_kernel<<<gg, 256, 0, stream>>>(af, wq, sz, part);

    dim3 gr(OUT_F / 256, M_TOK);                 // 43 x 32
    reduce_kernel<<<gr, 256, 0, stream>>>(part, bias, out);
}

// Round 8
// 265.475 us; speedup vs baseline: 1.1114x; 1.0152x over previous
//
#include <hip/hip_runtime.h>
#include <hip/hip_bf16.h>
#include <stdint.h>

#define M_TOK 32
#define IN_F 4096
#define OUT_F 11008
#define NSPLIT 8
#define KRANGE (IN_F / NSPLIT)   // 512 k per block
#define NSTEP  (KRANGE / 32)     // 16 MFMA k-steps per block
#define NKK    (IN_F / 32)       // 128 global k-steps
#define NBUF   4                 // weight LDS tile ring (3 tiles in flight)

typedef __attribute__((ext_vector_type(8))) short bf16x8;
typedef __attribute__((ext_vector_type(4))) float f32x4;

__device__ inline uint32_t pack_bf16(float a, float b) {
    __hip_bfloat16 ha = __float2bfloat16(a);
    __hip_bfloat16 hb = __float2bfloat16(b);
    uint16_t ua = *(uint16_t*)&ha;
    uint16_t ub = *(uint16_t*)&hb;
    return (uint32_t)ua | ((uint32_t)ub << 16);
}

// Merged prep: blocks 0..1375 -> out[m][o] = bias[o] (exact cover 32 x 11008);
// blocks 1376..1407 -> pack x into MFMA A-fragments (bf16), fragment-ordered:
// af[kk*128 + j*64 + lane]; lane (lm,lq) of frag j holds
// x[m = lm + 16*j][kk*32 + lq*8 .. +8] as bf16x8.
__global__ void prep_kernel(const float* __restrict__ bias, float* __restrict__ out,
                            const float* __restrict__ x, uint4* __restrict__ ws4) {
    const int b = blockIdx.x;
    const int t = threadIdx.x;
    if (b < (OUT_F / 256) * M_TOK) {                 // 1376 bias-init blocks
        int o = (b % (OUT_F / 256)) * 256 + t;
        int m = b / (OUT_F / 256);
        out[(size_t)m * OUT_F + o] = bias[o];
        return;
    }
    int u  = (b - (OUT_F / 256) * M_TOK) * 256 + t;  // 0..8191
    int kk = u >> 6;
    int l  = u & 63;
    int lm = l & 15;
    int lq = l >> 4;
    int kb = kk * 32 + lq * 8;
    #pragma unroll
    for (int j = 0; j < 2; ++j) {
        const float* xp = x + (size_t)(lm + 16 * j) * IN_F + kb;
        union { uint4 q; uint32_t u[4]; } f;
        f.u[0] = pack_bf16(xp[0], xp[1]);
        f.u[1] = pack_bf16(xp[2], xp[3]);
        f.u[2] = pack_bf16(xp[4], xp[5]);
        f.u[3] = pack_bf16(xp[6], xp[7]);
        ws4[(size_t)kk * 128 + j * 64 + l] = f.q;
    }
}

// Deep-pipelined dequant-GEMM (R4 structure, best verified: 265.8 us).
// The MAIN LOOP'S ONLY VMEM ops are the staged weight loads, so the counted
// vmcnt(4) is exact (R3 lesson: any per-step global load sits behind the
// staged tiles in the in-order vmcnt queue and its compiler-inserted wait
// drains the whole pipeline).
//   prologue: stage A-frags (32 KB) + sz slice (8 KB) + weight tiles 0-2
//   per step: vmcnt(4) -> s_barrier -> STAGE(s+3) -> ds_reads+dequant+2 MFMA
// LDS: 32 KB weights (4-ring) + 32 KB A + 8 KB sz = 72 KB -> 2 blocks/CU.
// Epilogue: per-lane atomicAdd (R7 falsified the atomic-cost theory: the
// partials+reduce variant was +3.7 us).
__launch_bounds__(256)
__global__ void qgemm_kernel(const uint4* __restrict__ af,
                             const int* __restrict__ wq,
                             const float* __restrict__ sz,
                             float* __restrict__ out) {
    __shared__ int    lds_w[NBUF][64 * 32];   // 4 x 8 KB weight tiles
    __shared__ uint4  lds_a[NSTEP * 128];     // 32 KB A-fragments (this ks slice)
    __shared__ float2 lds_s[NSTEP * 64];      // 8 KB scale/zero (step-major)

    const int bid = blockIdx.x;
    const int ks  = bid & (NSPLIT - 1);
    const int nb  = bid >> 3;
    const int t   = threadIdx.x;
    const int wv  = t >> 6;
    const int l   = t & 63;
    const int lm  = l & 15;
    const int lq  = l >> 4;

    const int row0 = nb * 64;
    const int row  = row0 + wv * 16 + lm;    // out-feature row this lane computes
    const int k0   = ks * KRANGE;

    // weight staging: thread t covers tile row rs = t>>3 (+32 for issue 1),
    // chunk slot cs = t&7; fetch global chunk (cs ^ (rs&7)) so LDS slot c of
    // row r holds global chunk c^(r&7) (involution; kills 16-way read conflict).
    const int rs    = t >> 3;                // 0..31
    const int cs    = t & 7;
    const int* gw0  = wq + (size_t)(row0 + rs) * IN_F + k0 + ((cs ^ (rs & 7)) * 4);
    const int* gw1  = gw0 + (size_t)32 * IN_F;   // rows 32..63

#define GLL(src, dst) \
    __builtin_amdgcn_global_load_lds( \
        (const __attribute__((address_space(1))) int*)(src), \
        (__attribute__((address_space(3))) int*)(dst), 16, 0, 0)

#define STAGE(buf, tile) do {                                 \
    GLL(gw0 + (tile) * 32, &lds_w[(buf)][wv * 256]);          \
    GLL(gw1 + (tile) * 32, &lds_w[(buf)][1024 + wv * 256]);   \
} while (0)

#define WAITV(N) do {                                         \
    asm volatile("s_waitcnt vmcnt(" #N ")" ::: "memory");     \
    __builtin_amdgcn_sched_barrier(0);                        \
} while (0)

#define BAR() do {                                            \
    __builtin_amdgcn_s_barrier();                             \
    __builtin_amdgcn_sched_barrier(0);                        \
} while (0)

    // weight reader addresses (swizzle inverted): lane wants global chunks
    // 2*lq and 2*lq+1 of local row rloc.
    const int rloc = wv * 16 + lm;
    const int c0   = rloc * 32 + (((2 * lq)     ^ (rloc & 7)) * 4);
    const int c1   = rloc * 32 + (((2 * lq + 1) ^ (rloc & 7)) * 4);

    // ---- prologue staging (order matters for the vmcnt ledger) ----
    // A-frags: ks slice = af[ks*2048 .. +2048) uint4, contiguous 32 KB.
    {
        const uint4* asrc = af + (size_t)ks * (NSTEP * 128) + t;
        #pragma unroll
        for (int i = 0; i < 8; ++i)
            GLL(asrc + i * 256, &lds_a[i * 256 + wv * 64]);
    }
    // sz: step st, rows row0..row0+63 => 512 B contiguous per step.
    // thread t: st = t>>5 (+8 for issue 1), 16-B chunk c = t&31.
    {
        const float* szsrc = sz + ((size_t)(k0 >> 5) * OUT_F + row0) * 2
                                + (size_t)(t >> 5) * OUT_F * 2 + (t & 31) * 4;
        GLL(szsrc,                         &lds_s[wv * 128]);
        GLL(szsrc + (size_t)8 * OUT_F * 2, &lds_s[512 + wv * 128]);
    }
    STAGE(0, 0);
    STAGE(1, 1);
    STAGE(2, 2);
    __builtin_amdgcn_sched_barrier(0);
    // outstanding: A(8) + sz(2) + w(6) = 16. First WAITV(4) retires A, sz, tile0.

    f32x4 acc0 = {0.f, 0.f, 0.f, 0.f};
    f32x4 acc1 = {0.f, 0.f, 0.f, 0.f};

#define STEP_BODY(cb, st) do {                                                  \
    int4   q0 = *(const int4*)(&lds_w[(cb)][c0]);                               \
    int4   q1 = *(const int4*)(&lds_w[(cb)][c1]);                               \
    union { uint4 q; bf16x8 v; } a0, a1;                                        \
    a0.q = lds_a[(st) * 128 + l];                                               \
    a1.q = lds_a[(st) * 128 + 64 + l];                                          \
    float2 sv = lds_s[(st) * 64 + rloc];                                        \
    const float sc = sv.x;                                                      \
    const float zp = sv.y - 8.0f * sv.x;                                        \
    union { bf16x8 v; uint32_t u[4]; } bf;                                      \
    bf.u[0] = pack_bf16((float)q0.x * sc + zp, (float)q0.y * sc + zp);          \
    bf.u[1] = pack_bf16((float)q0.z * sc + zp, (float)q0.w * sc + zp);          \
    bf.u[2] = pack_bf16((float)q1.x * sc + zp, (float)q1.y * sc + zp);          \
    bf.u[3] = pack_bf16((float)q1.z * sc + zp, (float)q1.w * sc + zp);          \
    acc0 = __builtin_amdgcn_mfma_f32_16x16x32_bf16(a0.v, bf.v, acc0, 0, 0, 0);  \
    acc1 = __builtin_amdgcn_mfma_f32_16x16x32_bf16(a1.v, bf.v, acc1, 0, 0, 0);  \
} while (0)

    // main: steps 0..11, stage tiles 3..14; tiles s+1,s+2,(s+3) stay in flight
    #pragma unroll 4
    for (int s = 0; s < 12; ++s) {
        WAITV(4);                        // tile s staged; 4 loads outstanding
        BAR();
        STAGE((s + 3) & 3, s + 3);       // overwrites tile s-1's buffer (safe)
        STEP_BODY(s & 3, s);
    }
    // step 12: stage the last tile (15)
    WAITV(4); BAR(); STAGE(3, 15); STEP_BODY(0, 12);
    // steps 13..15: drain
    WAITV(4); BAR(); STEP_BODY(1, 13);
    WAITV(2); BAR(); STEP_BODY(2, 14);
    WAITV(0); BAR(); STEP_BODY(3, 15);

#undef STEP_BODY
#undef STAGE
#undef GLL
#undef WAITV
#undef BAR

    // epilogue: D col(lane&15)=n, row((lane>>4)*4+i)=m  (verified R0)
    const int ocol = row;
    #pragma unroll
    for (int i = 0; i < 4; ++i) {
        int m0 = lq * 4 + i;
        atomicAdd(&out[(size_t)m0 * OUT_F + ocol], acc0[i]);
        atomicAdd(&out[(size_t)(16 + m0) * OUT_F + ocol], acc1[i]);
    }
}

extern "C" void kernel_launch(void* const* d_in, const int* in_sizes, int n_in,
                              void* d_out, int out_size, void* d_ws, size_t ws_size,
                              hipStream_t stream) {
    const float* x    = (const float*)d_in[0];   // [32, 4096] fp32
    const int*   wq   = (const int*)d_in[1];     // [11008, 4096] int32 (0..15)
    const float* sz   = (const float*)d_in[2];   // [128, 11008, 2] fp32
    const float* bias = (const float*)d_in[3];   // [11008] fp32
    float* out = (float*)d_out;                  // [32, 11008] fp32
    uint4* af  = (uint4*)d_ws;                   // [128][2][64] bf16x8 A-frags (256 KB)

    // merged bias-init + A-frag prepack (one dispatch instead of two)
    prep_kernel<<<dim3((OUT_F / 256) * M_TOK + NKK * 64 / 256), 256, 0, stream>>>(
        bias, out, x, af);

    dim3 gg((OUT_F / 64) * NSPLIT);              // 172 * 8 = 1376 blocks
    qgemm_kernel<<<gg, 256, 0, stream>>>(af, wq, sz, out);
}